// Round 6
// baseline (405.282 us; speedup 1.0000x reference)
//
#include <hip/hip_runtime.h>
#include <hip/hip_bf16.h>

// Problem constants (b=4, n=4, c=256, h=w=64, k=128, out_c=256) — all I/O fp32
#define B   4
#define NN  4
#define C   256
#define HH  64
#define WW  64
#define L   4096      // H*W
#define NL  16384     // NN*L
#define K   128
#define OC  256
#define IC2 512       // 2*C
#define EPSV 1e-6f
#define PW  66        // padded width/height
#define PA  4356      // 66*66

typedef __hip_bfloat16 bf16;
typedef __attribute__((ext_vector_type(8))) __bf16 bf16x8;
typedef __attribute__((ext_vector_type(4))) float f32x4;

#define AS1(p) ((const __attribute__((address_space(1))) void*)(p))
#define AS3(p) ((__attribute__((address_space(3))) void*)(p))

// ---------------- init: mu_f/mu_bf [b][k][c] from mu0 [c][k] --------------------------------
__global__ void k_init(const float* __restrict__ mu0, float* __restrict__ mu_f,
                       bf16* __restrict__ mub) {
    int i = blockIdx.x * 256 + threadIdx.x;        // over B*128*256
    int rem = i & 32767;
    int k = rem >> 8, c = rem & 255;
    float v = mu0[c * 128 + k];
    mu_f[i] = v;
    mub[i]  = __float2bfloat16(v);
}

// ---------------- x fp32 [b][c][l] -> x_bf [b][c][l] + xt [b][l][c] bf16 --------------------
__global__ void k_prepx(const float* __restrict__ x, bf16* __restrict__ xb,
                        bf16* __restrict__ xt) {
    __shared__ float ld[64][65];
    int lt = blockIdx.x, ct = blockIdx.y, b = blockIdx.z;
    int t = threadIdx.x;
    #pragma unroll
    for (int i = 0; i < 16; i++) {
        int idx = t + i * 256;
        int ch = idx >> 6, xl = idx & 63;
        size_t a = ((size_t)b * C + ct * 64 + ch) * L + lt * 64 + xl;
        float v = x[a];
        ld[ch][xl] = v;
        xb[a] = __float2bfloat16(v);
    }
    __syncthreads();
    #pragma unroll
    for (int i = 0; i < 16; i++) {
        int idx = t + i * 256;
        int xl = idx >> 6, ch = idx & 63;
        xt[((size_t)b * L + lt * 64 + xl) * 256 + ct * 64 + ch] = __float2bfloat16(ld[ch][xl]);
    }
}

// ---------------- qy fp32 [img][c][l] -> P2 interior ch<256 (bf16, ch-innermost) ------------
__global__ void k_prepq(const float* __restrict__ qy, bf16* __restrict__ P2) {
    __shared__ float ld[64][65];
    int y = blockIdx.x, ct = blockIdx.y, img = blockIdx.z;
    int t = threadIdx.x;
    #pragma unroll
    for (int i = 0; i < 16; i++) {
        int idx = t + i * 256;
        int ch = idx >> 6, xl = idx & 63;
        ld[ch][xl] = qy[((size_t)img * C + ct * 64 + ch) * L + y * WW + xl];
    }
    __syncthreads();
    #pragma unroll
    for (int i = 0; i < 16; i++) {
        int idx = t + i * 256;
        int xl = idx >> 6, ch = idx & 63;
        P2[((size_t)img * PA + (size_t)(y + 1) * PW + xl + 1) * 512 + ct * 64 + ch] =
            __float2bfloat16(ld[ch][xl]);
    }
}

// ---------------- zero only the P2 border pixels (all 512 ch) -------------------------------
__global__ void k_zborder(uint4* __restrict__ P2) {
    int pi = blockIdx.x, img = blockIdx.y, t = threadIdx.x;  // 64 threads, 64 uint4/pixel
    int y, x;
    if      (pi < 66)  { y = 0;        x = pi; }
    else if (pi < 132) { y = 65;       x = pi - 66; }
    else if (pi < 196) { y = pi - 131; x = 0; }
    else               { y = pi - 195; x = 65; }
    P2[((size_t)img * PA + (size_t)y * PW + x) * 64 + t] = uint4{0, 0, 0, 0};
}

// ---------------- weights: cw fp32 [oc][ic][3][3] -> Wb bf16 [r][oc][ic] --------------------
__global__ void k_wprep(const float* __restrict__ cw, bf16* __restrict__ wb) {
    int idx = blockIdx.x * 256 + threadIdx.x;
    if (idx >= 9 * OC * IC2) return;
    int r  = idx / (OC * IC2);
    int oc = (idx / IC2) & 255;
    int ic = idx & 511;
    wb[idx] = __float2bfloat16(cw[((size_t)oc * IC2 + ic) * 9 + r]);
}

// ---------------- EM A (MFMA): zt[b][k][l] = softmax_k( mu[k][:] . xt[l][:] ) ---------------
// block: 128k x 64l; wave w owns 16 l (B-frag) x all 128 k (8 A-frags)
__global__ void __launch_bounds__(256) k_z(const bf16* __restrict__ xt,
                                           const bf16* __restrict__ mub,
                                           bf16* __restrict__ zt) {
    __shared__ __align__(16) char smem[12288];
    char* tA = smem;          // mu tile 128x32 = 8KB
    char* tB = smem + 8192;   // xt tile 64x32  = 4KB
    int t = threadIdx.x, w = t >> 6, lane = t & 63;
    int b = blockIdx.y, l0 = blockIdx.x * 64;
    const bf16* Ab = mub + (size_t)b * K * C;
    const bf16* Bb = xt + ((size_t)b * L + l0) * C;
    int srow = t >> 2, sseg = t & 3, aseg = sseg ^ (srow & 3);
    char* dA0 = tA + w * 1024;
    char* dA1 = tA + 4096 + w * 1024;
    char* dB  = tB + w * 1024;
    int aoff[8], boff;
    #pragma unroll
    for (int i = 0; i < 8; i++) {
        int rowA = i * 16 + (lane & 15);
        aoff[i] = rowA * 64 + (((lane >> 4) ^ (rowA & 3)) << 4);
    }
    { int rowB = w * 16 + (lane & 15);
      boff = rowB * 64 + (((lane >> 4) ^ (rowB & 3)) << 4); }
    f32x4 acc[8];
    #pragma unroll
    for (int i = 0; i < 8; i++) acc[i] = f32x4{0.f, 0.f, 0.f, 0.f};
    for (int s = 0; s < 8; s++) {
        int cb0 = s * 32 + aseg * 8;
        __syncthreads();
        __builtin_amdgcn_global_load_lds(AS1(Ab + (size_t)srow * C + cb0),        AS3(dA0), 16, 0, 0);
        __builtin_amdgcn_global_load_lds(AS1(Ab + (size_t)(srow + 64) * C + cb0), AS3(dA1), 16, 0, 0);
        __builtin_amdgcn_global_load_lds(AS1(Bb + (size_t)srow * C + cb0),        AS3(dB),  16, 0, 0);
        __syncthreads();
        bf16x8 bfr = *(bf16x8*)(tB + boff);
        #pragma unroll
        for (int i = 0; i < 8; i++) {
            bf16x8 af = *(bf16x8*)(tA + aoff[i]);
            acc[i] = __builtin_amdgcn_mfma_f32_16x16x32_bf16(af, bfr, acc[i], 0, 0, 0);
        }
    }
    // softmax over k (i, r, quad) per column l = lane&15
    float m = -1e30f;
    #pragma unroll
    for (int i = 0; i < 8; i++)
        #pragma unroll
        for (int r = 0; r < 4; r++) m = fmaxf(m, acc[i][r]);
    m = fmaxf(m, __shfl_xor(m, 16, 64));
    m = fmaxf(m, __shfl_xor(m, 32, 64));
    float ssum = 0.f;
    #pragma unroll
    for (int i = 0; i < 8; i++)
        #pragma unroll
        for (int r = 0; r < 4; r++) { acc[i][r] = __expf(acc[i][r] - m); ssum += acc[i][r]; }
    ssum += __shfl_xor(ssum, 16, 64);
    ssum += __shfl_xor(ssum, 32, 64);
    float inv = 1.f / ssum;
    int quad = lane >> 4, col = lane & 15;
    bf16* zb = zt + (size_t)b * K * L + l0 + w * 16 + col;
    #pragma unroll
    for (int i = 0; i < 8; i++)
        #pragma unroll
        for (int r = 0; r < 4; r++) {
            int k = i * 16 + quad * 4 + r;
            zb[(size_t)k * L] = __float2bfloat16(acc[i][r] * inv);
        }
}

// ---------------- EM B (MFMA, split-K 16, c-split 4): part[b][ch][k][c] = sum_l zt*x --------
__global__ void __launch_bounds__(256) k_mu(const bf16* __restrict__ zt,
                                            const bf16* __restrict__ xb,
                                            float* __restrict__ part) {
    __shared__ __align__(16) char smem[12288];
    char* tA = smem;          // zt tile 128x32 = 8KB
    char* tB = smem + 8192;   // xb tile 64x32  = 4KB
    int t = threadIdx.x, w = t >> 6, lane = t & 63;
    int ct = blockIdx.x, chunk = blockIdx.y, b = blockIdx.z;   // (4,16,4)
    const bf16* Ab = zt + (size_t)b * K * L + chunk * 256;
    const bf16* Bb = xb + ((size_t)b * C + ct * 64) * L + chunk * 256;
    int srow = t >> 2, sseg = t & 3, aseg = sseg ^ (srow & 3);
    char* dA0 = tA + w * 1024; char* dA1 = tA + 4096 + w * 1024;
    char* dB0 = tB + w * 1024;
    int wm = w >> 1, wn = w & 1;
    int aoff[4], boff[2];
    #pragma unroll
    for (int i = 0; i < 4; i++) {
        int rowA = wm * 64 + i * 16 + (lane & 15);
        aoff[i] = rowA * 64 + (((lane >> 4) ^ (rowA & 3)) << 4);
    }
    #pragma unroll
    for (int j = 0; j < 2; j++) {
        int rowB = wn * 32 + j * 16 + (lane & 15);
        boff[j] = rowB * 64 + (((lane >> 4) ^ (rowB & 3)) << 4);
    }
    f32x4 acc[4][2];
    #pragma unroll
    for (int i = 0; i < 4; i++)
        #pragma unroll
        for (int j = 0; j < 2; j++) acc[i][j] = f32x4{0.f, 0.f, 0.f, 0.f};
    for (int s = 0; s < 8; s++) {
        int lb = s * 32 + aseg * 8;
        __syncthreads();
        __builtin_amdgcn_global_load_lds(AS1(Ab + (size_t)srow * L + lb),        AS3(dA0), 16, 0, 0);
        __builtin_amdgcn_global_load_lds(AS1(Ab + (size_t)(srow + 64) * L + lb), AS3(dA1), 16, 0, 0);
        __builtin_amdgcn_global_load_lds(AS1(Bb + (size_t)srow * L + lb),        AS3(dB0), 16, 0, 0);
        __syncthreads();
        bf16x8 af[4], bfr[2];
        #pragma unroll
        for (int i = 0; i < 4; i++) af[i]  = *(bf16x8*)(tA + aoff[i]);
        #pragma unroll
        for (int j = 0; j < 2; j++) bfr[j] = *(bf16x8*)(tB + boff[j]);
        #pragma unroll
        for (int i = 0; i < 4; i++)
            #pragma unroll
            for (int j = 0; j < 2; j++)
                acc[i][j] = __builtin_amdgcn_mfma_f32_16x16x32_bf16(af[i], bfr[j], acc[i][j], 0, 0, 0);
    }
    float* pb = part + ((size_t)(b * 16 + chunk) * K) * C + ct * 64;
    int quad = lane >> 4, col = lane & 15;
    #pragma unroll
    for (int i = 0; i < 4; i++) {
        int k = wm * 64 + i * 16 + quad * 4;
        #pragma unroll
        for (int j = 0; j < 2; j++) {
            int c = wn * 32 + j * 16 + col;
            #pragma unroll
            for (int r = 0; r < 4; r++)
                pb[(size_t)(k + r) * C + c] = acc[i][j][r];
        }
    }
}

// ---------------- reduce partials + l2norm over c; emit mu_f, mu_bf [k][c], muT [c][k] ------
__global__ void k_norm(const float* __restrict__ part, float* __restrict__ mu_f,
                       bf16* __restrict__ mub, bf16* __restrict__ muT) {
    int b = blockIdx.x >> 7, k = blockIdx.x & 127, lane = threadIdx.x;  // 64 thr
    float v[4] = {0.f, 0.f, 0.f, 0.f};
    for (int ch = 0; ch < 16; ch++) {
        const float* p = part + ((size_t)(b * 16 + ch) * K + k) * C;
        #pragma unroll
        for (int j = 0; j < 4; j++) v[j] += p[lane + j * 64];
    }
    float s = v[0]*v[0] + v[1]*v[1] + v[2]*v[2] + v[3]*v[3];
    for (int o = 32; o > 0; o >>= 1) s += __shfl_xor(s, o, 64);
    float r = 1.f / (EPSV + sqrtf(s));
    float* mf = mu_f + ((size_t)b * K + k) * C;
    bf16*  mb = mub  + ((size_t)b * K + k) * C;
    bf16*  mt = muT  + (size_t)b * C * K + k;
    #pragma unroll
    for (int j = 0; j < 4; j++) {
        float val = v[j] * r;
        int c = lane + j * 64;
        mf[c] = val;
        mb[c] = __float2bfloat16(val);
        mt[(size_t)c * K] = __float2bfloat16(val);
    }
}

// ---------------- FUSED q_z + rec: one block = one (img,row y): 64 l' x 128 k ---------------
// Phase 1 (= old k_qz): acc[j][r] = softmax_k( q[l'][:] . mu[k][:] ), l' = w*16+quad*4+r,
//   k = j*16+col. Phase 2: route z through padded LDS tile (64 x 272B) to A-frag layout
//   (row = lane&15, k = quad*8+e), stage muT [256 c][32 k] per chunk (linear gload_lds dest,
//   XOR-involution seg swizzle), rec[l'][c] = sum_k z*muT -> store P2 ch256+ directly.
// Kills the 16.8 MB qz HBM round-trip + the whole k_rec launch.
__global__ void __launch_bounds__(256) k_qzrec(const bf16* __restrict__ P2r,
                                               const bf16* __restrict__ mub,
                                               const bf16* __restrict__ muT,
                                               bf16* __restrict__ P2w) {
    __shared__ __align__(16) char smem[46080];
    char* tA = smem;           // q tile 64x32 = 4KB
    char* tB = smem + 4096;    // mu tile 128x32 = 8KB
    char* zl = smem + 12288;   // z tile 64 x 272B = 17408 (pad kills b128-read conflicts)
    char* mt = smem + 29696;   // muT tile 256 x 64B = 16384
    int t = threadIdx.x, w = t >> 6, lane = t & 63;
    int b = blockIdx.y, tile = blockIdx.x;          // 0..255
    int n = tile >> 6, y = tile & 63;
    int img = b * NN + n;
    const bf16* Ab = P2r + ((size_t)img * PA + (size_t)(y + 1) * PW + 1) * 512;
    const bf16* Bb = mub + (size_t)b * K * C;
    int srow = t >> 2, sseg = t & 3, aseg = sseg ^ (srow & 3);
    char* dA  = tA + w * 1024;
    char* dB0 = tB + w * 1024;
    char* dB1 = tB + 4096 + w * 1024;
    int q = lane >> 4, col = lane & 15;
    int boff[8], aoff;
    #pragma unroll
    for (int j = 0; j < 8; j++) {
        int rowB = j * 16 + col;
        boff[j] = rowB * 64 + ((q ^ (rowB & 3)) << 4);
    }
    { int rowA = w * 16 + col;
      aoff = rowA * 64 + ((q ^ (rowA & 3)) << 4); }
    f32x4 acc[8];
    #pragma unroll
    for (int j = 0; j < 8; j++) acc[j] = f32x4{0.f, 0.f, 0.f, 0.f};
    for (int s = 0; s < 8; s++) {
        int cb0 = s * 32 + aseg * 8;
        __syncthreads();
        __builtin_amdgcn_global_load_lds(AS1(Ab + (size_t)srow * 512 + cb0),      AS3(dA),  16, 0, 0);
        __builtin_amdgcn_global_load_lds(AS1(Bb + (size_t)srow * C + cb0),        AS3(dB0), 16, 0, 0);
        __builtin_amdgcn_global_load_lds(AS1(Bb + (size_t)(srow + 64) * C + cb0), AS3(dB1), 16, 0, 0);
        __syncthreads();
        bf16x8 af = *(bf16x8*)(tA + aoff);
        #pragma unroll
        for (int j = 0; j < 8; j++) {
            bf16x8 bfr = *(bf16x8*)(tB + boff[j]);
            acc[j] = __builtin_amdgcn_mfma_f32_16x16x32_bf16(af, bfr, acc[j], 0, 0, 0);
        }
    }
    // softmax over k (j, col) per row r; write z into zl[l'][k] (bf16, row stride 272)
    #pragma unroll
    for (int r = 0; r < 4; r++) {
        float mm = acc[0][r];
        #pragma unroll
        for (int j = 1; j < 8; j++) mm = fmaxf(mm, acc[j][r]);
        mm = fmaxf(mm, __shfl_xor(mm, 1, 64));
        mm = fmaxf(mm, __shfl_xor(mm, 2, 64));
        mm = fmaxf(mm, __shfl_xor(mm, 4, 64));
        mm = fmaxf(mm, __shfl_xor(mm, 8, 64));
        float ss = 0.f;
        float e[8];
        #pragma unroll
        for (int j = 0; j < 8; j++) { e[j] = __expf(acc[j][r] - mm); ss += e[j]; }
        ss += __shfl_xor(ss, 1, 64);
        ss += __shfl_xor(ss, 2, 64);
        ss += __shfl_xor(ss, 4, 64);
        ss += __shfl_xor(ss, 8, 64);
        float inv = 1.f / ss;
        int zrow = w * 16 + q * 4 + r;
        #pragma unroll
        for (int j = 0; j < 8; j++)
            *(bf16*)(zl + zrow * 272 + (j * 16 + col) * 2) = __float2bfloat16(e[j] * inv);
    }
    // stage muT chunk 0: per wave it2: rows w*64+it2*16.. (16 rows x 4 segs = 64 lanes, linear dst)
    const bf16* Mb = muT + (size_t)b * C * K;
    int mrow = (lane >> 2);            // 0..15 within group
    int mseg = lane & 3;
    #pragma unroll
    for (int it2 = 0; it2 < 4; it2++) {
        int row = w * 64 + it2 * 16 + mrow;
        int sg = mseg ^ ((row ^ (row >> 2)) & 3);
        __builtin_amdgcn_global_load_lds(AS1(Mb + (size_t)row * K + sg * 8),
            AS3(mt + (w * 64 + it2 * 16) * 64), 16, 0, 0);
    }
    __syncthreads();
    // A-frags from zl: row = w*16+col, k = ch*32 + q*8..+8
    bf16x8 afz[4];
    #pragma unroll
    for (int ch = 0; ch < 4; ch++)
        afz[ch] = *(bf16x8*)(zl + (w * 16 + col) * 272 + ch * 64 + q * 16);
    f32x4 acc2[16];
    #pragma unroll
    for (int j = 0; j < 16; j++) acc2[j] = f32x4{0.f, 0.f, 0.f, 0.f};
    for (int s = 0; s < 4; s++) {
        #pragma unroll
        for (int j = 0; j < 16; j++) {
            int rr = j * 16 + col;
            bf16x8 bm = *(bf16x8*)(mt + rr * 64 + ((q ^ ((rr ^ (rr >> 2)) & 3)) << 4));
            acc2[j] = __builtin_amdgcn_mfma_f32_16x16x32_bf16(afz[s], bm, acc2[j], 0, 0, 0);
        }
        if (s < 3) {
            __syncthreads();
            #pragma unroll
            for (int it2 = 0; it2 < 4; it2++) {
                int row = w * 64 + it2 * 16 + mrow;
                int sg = mseg ^ ((row ^ (row >> 2)) & 3);
                __builtin_amdgcn_global_load_lds(AS1(Mb + (size_t)row * K + (s + 1) * 32 + sg * 8),
                    AS3(mt + (w * 64 + it2 * 16) * 64), 16, 0, 0);
            }
            __syncthreads();
        }
    }
    // store rec to P2 second-half channels; l' = w*16 + q*4 + r, c = j*16 + col
    #pragma unroll
    for (int r = 0; r < 4; r++) {
        int xg = w * 16 + q * 4 + r;
        bf16* dst = P2w + ((size_t)img * PA + (size_t)(y + 1) * PW + xg + 1) * 512 + 256;
        #pragma unroll
        for (int j = 0; j < 16; j++)
            dst[j * 16 + col] = __float2bfloat16(acc2[j][r]);
    }
}

// ---------------- MFMA implicit-GEMM conv: 128oc x 256px (4 out rows) per block -------------
// (R3/R5 version — best measured.) Per step each wave does 32 MFMA from 12 ds_read_b128.
// IN tile [6 rows][66 px][32 ic] = 25344 B staged per chunk; W streams via 3 x 8192 B
// buffers (prefetch distance 2, counted vmcnt(2)). Grid 512 = exactly 2 blocks/CU.
__global__ void __launch_bounds__(256, 2) k_conv(const bf16* __restrict__ P2,
                                                 const bf16* __restrict__ Wb,
                                                 const float* __restrict__ cb,
                                                 float* __restrict__ out) {
    __shared__ __align__(16) char smem[49920];
    char* inl = smem;            // 6*66*32*2 = 25344 B input tile
    char* wld = smem + 25344;    // 3 x 8192 B weight buffers
    int t = threadIdx.x, w = t >> 6, lane = t & 63;
    int m0  = blockIdx.x * 128;
    int y0  = blockIdx.y * 4;    // padded rows y0..y0+5 feed output rows y0..y0+3
    int img = blockIdx.z;
    int srow = t >> 2;
    int aseg = (t & 3) ^ ((srow ^ (srow >> 2)) & 3);     // W stage swizzle (64B rows)
    int wm = w >> 1, wn = w & 1;                          // oc-half / px-half (2 rows)
    int q = lane >> 4, lane15 = lane & 15;

    // A (weights) LDS read offsets within one 8KB buffer (matches stage swizzle)
    int aoff[4];
    #pragma unroll
    for (int i = 0; i < 4; i++) {
        int rowA = wm * 64 + i * 16 + lane15;
        aoff[i] = rowA * 64 + (((q ^ (rowA ^ (rowA >> 2))) & 3) << 4);
    }

    // stage input chunk cc (32 ic): 6 rows x 66 px x 4 seg = 1584 x 16B, linear LDS dest.
    // LDS slot (row, px, s') holds global seg s' ^ ((px ^ (px>>1)) & 3)  (involution).
    auto stageIN = [&](int cc) {
        size_t ibase = (size_t)img * PA * 512 + cc * 32;
        #pragma unroll
        for (int it = 0; it < 6; it++) {
            unsigned g = it * 256 + t;
            unsigned row = g / 264u, ps = g - row * 264u;
            unsigned px = ps >> 2, s0 = ps & 3;
            unsigned sg = s0 ^ ((px ^ (px >> 1)) & 3);
            __builtin_amdgcn_global_load_lds(
                AS1(P2 + ibase + ((size_t)(y0 + row) * PW + px) * 512 + sg * 8),
                AS3(inl + it * 4096 + w * 1024), 16, 0, 0);
        }
        if (t < 48) {   // remainder 1536..1583 (wave 0, lanes 0-47)
            unsigned g = 1536 + t;
            unsigned row = g / 264u, ps = g - row * 264u;
            unsigned px = ps >> 2, s0 = ps & 3;
            unsigned sg = s0 ^ ((px ^ (px >> 1)) & 3);
            __builtin_amdgcn_global_load_lds(
                AS1(P2 + ibase + ((size_t)(y0 + row) * PW + px) * 512 + sg * 8),
                AS3(inl + 24576), 16, 0, 0);
        }
    };

    // acc init with bias: acc[i][j], i = oc-tile (4x16), j = px-tile (2 rows x 4x16)
    f32x4 acc[4][8];
    #pragma unroll
    for (int i = 0; i < 4; i++) {
        int oc = m0 + wm * 64 + i * 16 + q * 4;
        #pragma unroll
        for (int r = 0; r < 4; r++) {
            float bv = cb[oc + r];
            #pragma unroll
            for (int j = 0; j < 8; j++) acc[i][j][r] = bv;
        }
    }

    // prologue: IN(0) + W(tap0,cc0)->buf0, W(tap1,cc0)->buf1; full drain
    stageIN(0);
    {
        const bf16* w0 = Wb + (size_t)(m0 + srow) * IC2 + aseg * 8;
        __builtin_amdgcn_global_load_lds(AS1(w0),                         AS3(wld + w * 1024), 16, 0, 0);
        __builtin_amdgcn_global_load_lds(AS1(w0 + (size_t)64 * IC2),      AS3(wld + 4096 + w * 1024), 16, 0, 0);
        const bf16* w1 = w0 + (size_t)(OC * IC2);
        __builtin_amdgcn_global_load_lds(AS1(w1),                         AS3(wld + 8192 + w * 1024), 16, 0, 0);
        __builtin_amdgcn_global_load_lds(AS1(w1 + (size_t)64 * IC2),      AS3(wld + 8192 + 4096 + w * 1024), 16, 0, 0);
    }
    asm volatile("s_waitcnt vmcnt(0)" ::: "memory");
    __builtin_amdgcn_s_barrier();
    asm volatile("" ::: "memory");

    for (int cc = 0; cc < 16; cc++) {
        #pragma unroll
        for (int rt = 0; rt < 9; rt++) {
            const int dy = rt / 3, dx = rt % 3;
            // ---- W fragments (buffer idx static: rt % 3) ----
            char* wbuf = wld + (rt % 3) * 8192;
            bf16x8 af[4];
            #pragma unroll
            for (int i = 0; i < 4; i++) af[i] = *(bf16x8*)(wbuf + aoff[i]);
            // ---- prefetch W(global step +2) into buffer (rt+2)%3 (prev step's, safe) ----
            const bool doPf = (cc * 9 + rt + 2) < 144;
            if (doPf) {
                const int g2 = rt + 2;
                const int rt2 = (g2 >= 9) ? g2 - 9 : g2;
                const int cc2 = cc + (g2 >= 9 ? 1 : 0);
                char* wdst = wld + ((rt + 2) % 3) * 8192;
                const bf16* wsrc = Wb + (size_t)rt2 * (OC * IC2) + (size_t)(m0 + srow) * IC2
                                 + cc2 * 32 + aseg * 8;
                __builtin_amdgcn_global_load_lds(AS1(wsrc),                    AS3(wdst + w * 1024), 16, 0, 0);
                __builtin_amdgcn_global_load_lds(AS1(wsrc + (size_t)64 * IC2), AS3(wdst + 4096 + w * 1024), 16, 0, 0);
            }
            // ---- MFMA: j = (row 0/1 within px-half) x (4 px-tiles of 16) ----
            __builtin_amdgcn_s_setprio(1);
            #pragma unroll
            for (int j = 0; j < 8; j++) {
                int p = (j & 3) * 16 + lane15 + dx;
                int rowsel = 2 * wn + (j >> 2) + dy;
                bf16x8 bfr = *(bf16x8*)(inl + rowsel * 4224 + p * 64 +
                                        (((q ^ (p ^ (p >> 1))) & 3) << 4));
                #pragma unroll
                for (int i = 0; i < 4; i++)
                    acc[i][j] = __builtin_amdgcn_mfma_f32_16x16x32_bf16(af[i], bfr, acc[i][j], 0, 0, 0);
            }
            __builtin_amdgcn_s_setprio(0);
            // ---- waits + barriers ----
            if (rt == 8) {
                if (cc < 15) {   // chunk boundary: re-stage IN, full drain
                    asm volatile("" ::: "memory");
                    __builtin_amdgcn_s_barrier();
                    asm volatile("" ::: "memory");
                    stageIN(cc + 1);
                    asm volatile("s_waitcnt vmcnt(0)" ::: "memory");
                    __builtin_amdgcn_s_barrier();
                    asm volatile("" ::: "memory");
                }
                // cc==15: last step, fall through to epilogue
            } else {
                if (doPf) asm volatile("s_waitcnt vmcnt(2)" ::: "memory");
                else      asm volatile("s_waitcnt vmcnt(0)" ::: "memory");
                __builtin_amdgcn_s_barrier();
                asm volatile("" ::: "memory");
            }
        }
    }

    // epilogue: store (bias already in acc)
    #pragma unroll
    for (int i = 0; i < 4; i++) {
        int oc = m0 + wm * 64 + i * 16 + q * 4;
        #pragma unroll
        for (int j = 0; j < 8; j++) {
            int px = blockIdx.y * 256 + wn * 128 + (j >> 2) * 64 + (j & 3) * 16 + lane15;
            #pragma unroll
            for (int r = 0; r < 4; r++)
                out[((size_t)img * OC + oc + r) * L + px] = acc[i][j][r];
        }
    }
}

// ---------------- mu_f [b][k][c] -> out tail [b][c][k] fp32 ---------------------------------
__global__ void k_muout(const float* __restrict__ mu_f, float* __restrict__ out) {
    int i = blockIdx.x * 256 + threadIdx.x;       // over 131072, out index (b,c,k)
    int b = i >> 15, rem = i & 32767;
    int c = rem >> 7, k = rem & 127;
    out[(size_t)16777216 + i] = mu_f[((size_t)b * K + k) * C + c];
}

extern "C" void kernel_launch(void* const* d_in, const int* in_sizes, int n_in,
                              void* d_out, int out_size, void* d_ws, size_t ws_size,
                              hipStream_t stream) {
    const float* x   = (const float*)d_in[0];   // [4][256][4096]
    const float* qy  = (const float*)d_in[1];   // [16][256][4096]
    const float* mu0 = (const float*)d_in[2];   // [256][128]
    const float* cw  = (const float*)d_in[3];   // [256][512][3][3]
    const float* cb  = (const float*)d_in[4];   // [256]
    float* out = (float*)d_out;

    // workspace layout (bytes), total 91.6 MB:
    //   mu_f   @ 0         (512 KB fp32 [b][k][c])
    //   mu_bf  @ 524288    (256 KB bf16 [b][k][c])
    //   muT_bf @ 786432    (256 KB bf16 [b][c][k])
    //   Wb     @ 1048576   (2.25 MB bf16 [9][oc][ic])
    //   zt     @ 3407872   (EM zt bf16 [b][k][l] 4.19MB; dead after EM)
    //   P2     @ 20185088  (71.37 MB bf16 [16][66*66][512])
    //     EM-lifetime overlays inside P2: x_bf @+0 (8.39MB), part @+8388608 (8.39MB fp32),
    //     xt @+16777216 (8.39MB) — all dead before P2 is first written (after EM).
    char* ws = (char*)d_ws;
    float* mu_f = (float*)(ws);
    bf16*  mu_b = (bf16*) (ws + 524288);
    bf16*  muT  = (bf16*) (ws + 786432);
    bf16*  Wb   = (bf16*) (ws + 1048576);
    bf16*  zt   = (bf16*) (ws + 3407872);
    bf16*  P2   = (bf16*) (ws + 20185088);
    bf16*  x_bf = (bf16*) (ws + 20185088);
    float* part = (float*)(ws + 20185088 + 8388608);
    bf16*  xt   = (bf16*) (ws + 20185088 + 16777216);

    k_init<<<512, 256, 0, stream>>>(mu0, mu_f, mu_b);
    k_prepx<<<dim3(64, 4, 4), 256, 0, stream>>>(x, x_bf, xt);

    for (int it = 0; it < 5; it++) {
        k_z<<<dim3(64, 4), 256, 0, stream>>>(xt, mu_b, zt);
        k_mu<<<dim3(4, 16, 4), 256, 0, stream>>>(zt, x_bf, part);
        k_norm<<<512, 64, 0, stream>>>(part, mu_f, mu_b, muT);
    }

    k_prepq<<<dim3(64, 4, 16), 256, 0, stream>>>(qy, P2);
    k_zborder<<<dim3(260, 16), 64, 0, stream>>>((uint4*)P2);
    k_wprep<<<4608, 256, 0, stream>>>(cw, Wb);

    k_qzrec<<<dim3(256, 4), 256, 0, stream>>>(P2, mu_b, muT, P2);
    k_conv<<<dim3(2, 16, 16), 256, 0, stream>>>(P2, Wb, cb, out);
    k_muout<<<512, 256, 0, stream>>>(mu_f, out);
}

// Round 7
// 393.879 us; speedup vs baseline: 1.0290x; 1.0290x over previous
//
#include <hip/hip_runtime.h>
#include <hip/hip_bf16.h>

// Problem constants (b=4, n=4, c=256, h=w=64, k=128, out_c=256) — all I/O fp32
#define B   4
#define NN  4
#define C   256
#define HH  64
#define WW  64
#define L   4096      // H*W
#define NL  16384     // NN*L
#define K   128
#define OC  256
#define IC2 512       // 2*C
#define EPSV 1e-6f
#define PW  66        // padded width/height
#define PA  4356      // 66*66

typedef __hip_bfloat16 bf16;
typedef __attribute__((ext_vector_type(8))) __bf16 bf16x8;
typedef __attribute__((ext_vector_type(4))) float f32x4;

#define AS1(p) ((const __attribute__((address_space(1))) void*)(p))
#define AS3(p) ((__attribute__((address_space(3))) void*)(p))

// ---------------- init: mu_bf [b][k][c] from mu0 [c][k] -------------------------------------
__global__ void k_init(const float* __restrict__ mu0, bf16* __restrict__ mub) {
    int i = blockIdx.x * 256 + threadIdx.x;        // over B*128*256
    int rem = i & 32767;
    int k = rem >> 8, c = rem & 255;
    mub[i] = __float2bfloat16(mu0[c * 128 + k]);
}

// ---------------- x fp32 [b][c][l] -> x_bf [b][c][l] + xt [b][l][c] bf16 --------------------
__global__ void k_prepx(const float* __restrict__ x, bf16* __restrict__ xb,
                        bf16* __restrict__ xt) {
    __shared__ float ld[64][65];
    int lt = blockIdx.x, ct = blockIdx.y, b = blockIdx.z;
    int t = threadIdx.x;
    #pragma unroll
    for (int i = 0; i < 16; i++) {
        int idx = t + i * 256;
        int ch = idx >> 6, xl = idx & 63;
        size_t a = ((size_t)b * C + ct * 64 + ch) * L + lt * 64 + xl;
        float v = x[a];
        ld[ch][xl] = v;
        xb[a] = __float2bfloat16(v);
    }
    __syncthreads();
    #pragma unroll
    for (int i = 0; i < 16; i++) {
        int idx = t + i * 256;
        int xl = idx >> 6, ch = idx & 63;
        xt[((size_t)b * L + lt * 64 + xl) * 256 + ct * 64 + ch] = __float2bfloat16(ld[ch][xl]);
    }
}

// ---------------- merged: prepq (4096 blk) + zborder (1040 blk) + wprep (4608 blk) ----------
__global__ void k_mid(const float* __restrict__ qy, bf16* __restrict__ P2,
                      const float* __restrict__ cw, bf16* __restrict__ wb) {
    __shared__ float ld[64][65];
    int bid = blockIdx.x, t = threadIdx.x;
    if (bid < 4096) {
        // qy fp32 [img][c][l] -> P2 interior ch<256 (bf16, ch-innermost)
        int y = bid & 63, ct = (bid >> 6) & 3, img = bid >> 8;
        #pragma unroll
        for (int i = 0; i < 16; i++) {
            int idx = t + i * 256;
            int ch = idx >> 6, xl = idx & 63;
            ld[ch][xl] = qy[((size_t)img * C + ct * 64 + ch) * L + y * WW + xl];
        }
        __syncthreads();
        #pragma unroll
        for (int i = 0; i < 16; i++) {
            int idx = t + i * 256;
            int xl = idx >> 6, ch = idx & 63;
            P2[((size_t)img * PA + (size_t)(y + 1) * PW + xl + 1) * 512 + ct * 64 + ch] =
                __float2bfloat16(ld[ch][xl]);
        }
    } else if (bid < 5136) {
        // zero border pixels (all 512 ch); 4 pixels per block
        int zi = bid - 4096;
        int img = zi / 65, grp = zi - img * 65;
        int pi = grp * 4 + (t >> 6), tt = t & 63;
        int y, x;
        if      (pi < 66)  { y = 0;        x = pi; }
        else if (pi < 132) { y = 65;       x = pi - 66; }
        else if (pi < 196) { y = pi - 131; x = 0; }
        else               { y = pi - 195; x = 65; }
        ((uint4*)P2)[((size_t)img * PA + (size_t)y * PW + x) * 64 + tt] = uint4{0, 0, 0, 0};
    } else {
        // cw fp32 [oc][ic][3][3] -> Wb bf16 [r][oc][ic]
        int idx = (bid - 5136) * 256 + t;
        int r  = idx / (OC * IC2);
        int oc = (idx / IC2) & 255;
        int ic = idx & 511;
        wb[idx] = __float2bfloat16(cw[((size_t)oc * IC2 + ic) * 9 + r]);
    }
}

// ---------------- EM A (MFMA): zt[b][k][l] = softmax_k( mu[k][:] . xt[l][:] ) ---------------
// block: 128k x 64l; wave w owns 16 l (B-frag) x all 128 k (8 A-frags)
__global__ void __launch_bounds__(256) k_z(const bf16* __restrict__ xt,
                                           const bf16* __restrict__ mub,
                                           bf16* __restrict__ zt) {
    __shared__ __align__(16) char smem[12288];
    char* tA = smem;          // mu tile 128x32 = 8KB
    char* tB = smem + 8192;   // xt tile 64x32  = 4KB
    int t = threadIdx.x, w = t >> 6, lane = t & 63;
    int b = blockIdx.y, l0 = blockIdx.x * 64;
    const bf16* Ab = mub + (size_t)b * K * C;
    const bf16* Bb = xt + ((size_t)b * L + l0) * C;
    int srow = t >> 2, sseg = t & 3, aseg = sseg ^ (srow & 3);
    char* dA0 = tA + w * 1024;
    char* dA1 = tA + 4096 + w * 1024;
    char* dB  = tB + w * 1024;
    int aoff[8], boff;
    #pragma unroll
    for (int i = 0; i < 8; i++) {
        int rowA = i * 16 + (lane & 15);
        aoff[i] = rowA * 64 + (((lane >> 4) ^ (rowA & 3)) << 4);
    }
    { int rowB = w * 16 + (lane & 15);
      boff = rowB * 64 + (((lane >> 4) ^ (rowB & 3)) << 4); }
    f32x4 acc[8];
    #pragma unroll
    for (int i = 0; i < 8; i++) acc[i] = f32x4{0.f, 0.f, 0.f, 0.f};
    for (int s = 0; s < 8; s++) {
        int cb0 = s * 32 + aseg * 8;
        __syncthreads();
        __builtin_amdgcn_global_load_lds(AS1(Ab + (size_t)srow * C + cb0),        AS3(dA0), 16, 0, 0);
        __builtin_amdgcn_global_load_lds(AS1(Ab + (size_t)(srow + 64) * C + cb0), AS3(dA1), 16, 0, 0);
        __builtin_amdgcn_global_load_lds(AS1(Bb + (size_t)srow * C + cb0),        AS3(dB),  16, 0, 0);
        __syncthreads();
        bf16x8 bfr = *(bf16x8*)(tB + boff);
        #pragma unroll
        for (int i = 0; i < 8; i++) {
            bf16x8 af = *(bf16x8*)(tA + aoff[i]);
            acc[i] = __builtin_amdgcn_mfma_f32_16x16x32_bf16(af, bfr, acc[i], 0, 0, 0);
        }
    }
    // softmax over k (i, r, quad) per column l = lane&15
    float m = -1e30f;
    #pragma unroll
    for (int i = 0; i < 8; i++)
        #pragma unroll
        for (int r = 0; r < 4; r++) m = fmaxf(m, acc[i][r]);
    m = fmaxf(m, __shfl_xor(m, 16, 64));
    m = fmaxf(m, __shfl_xor(m, 32, 64));
    float ssum = 0.f;
    #pragma unroll
    for (int i = 0; i < 8; i++)
        #pragma unroll
        for (int r = 0; r < 4; r++) { acc[i][r] = __expf(acc[i][r] - m); ssum += acc[i][r]; }
    ssum += __shfl_xor(ssum, 16, 64);
    ssum += __shfl_xor(ssum, 32, 64);
    float inv = 1.f / ssum;
    int quad = lane >> 4, col = lane & 15;
    bf16* zb = zt + (size_t)b * K * L + l0 + w * 16 + col;
    #pragma unroll
    for (int i = 0; i < 8; i++)
        #pragma unroll
        for (int r = 0; r < 4; r++) {
            int k = i * 16 + quad * 4 + r;
            zb[(size_t)k * L] = __float2bfloat16(acc[i][r] * inv);
        }
}

// ---------------- EM B (MFMA, split-K 16, c-split 4): part[b][ch][k][c] = sum_l zt*x --------
__global__ void __launch_bounds__(256) k_mu(const bf16* __restrict__ zt,
                                            const bf16* __restrict__ xb,
                                            float* __restrict__ part) {
    __shared__ __align__(16) char smem[12288];
    char* tA = smem;          // zt tile 128x32 = 8KB
    char* tB = smem + 8192;   // xb tile 64x32  = 4KB
    int t = threadIdx.x, w = t >> 6, lane = t & 63;
    int ct = blockIdx.x, chunk = blockIdx.y, b = blockIdx.z;   // (4,16,4)
    const bf16* Ab = zt + (size_t)b * K * L + chunk * 256;
    const bf16* Bb = xb + ((size_t)b * C + ct * 64) * L + chunk * 256;
    int srow = t >> 2, sseg = t & 3, aseg = sseg ^ (srow & 3);
    char* dA0 = tA + w * 1024; char* dA1 = tA + 4096 + w * 1024;
    char* dB0 = tB + w * 1024;
    int wm = w >> 1, wn = w & 1;
    int aoff[4], boff[2];
    #pragma unroll
    for (int i = 0; i < 4; i++) {
        int rowA = wm * 64 + i * 16 + (lane & 15);
        aoff[i] = rowA * 64 + (((lane >> 4) ^ (rowA & 3)) << 4);
    }
    #pragma unroll
    for (int j = 0; j < 2; j++) {
        int rowB = wn * 32 + j * 16 + (lane & 15);
        boff[j] = rowB * 64 + (((lane >> 4) ^ (rowB & 3)) << 4);
    }
    f32x4 acc[4][2];
    #pragma unroll
    for (int i = 0; i < 4; i++)
        #pragma unroll
        for (int j = 0; j < 2; j++) acc[i][j] = f32x4{0.f, 0.f, 0.f, 0.f};
    for (int s = 0; s < 8; s++) {
        int lb = s * 32 + aseg * 8;
        __syncthreads();
        __builtin_amdgcn_global_load_lds(AS1(Ab + (size_t)srow * L + lb),        AS3(dA0), 16, 0, 0);
        __builtin_amdgcn_global_load_lds(AS1(Ab + (size_t)(srow + 64) * L + lb), AS3(dA1), 16, 0, 0);
        __builtin_amdgcn_global_load_lds(AS1(Bb + (size_t)srow * L + lb),        AS3(dB0), 16, 0, 0);
        __syncthreads();
        bf16x8 af[4], bfr[2];
        #pragma unroll
        for (int i = 0; i < 4; i++) af[i]  = *(bf16x8*)(tA + aoff[i]);
        #pragma unroll
        for (int j = 0; j < 2; j++) bfr[j] = *(bf16x8*)(tB + boff[j]);
        #pragma unroll
        for (int i = 0; i < 4; i++)
            #pragma unroll
            for (int j = 0; j < 2; j++)
                acc[i][j] = __builtin_amdgcn_mfma_f32_16x16x32_bf16(af[i], bfr[j], acc[i][j], 0, 0, 0);
    }
    float* pb = part + ((size_t)(b * 16 + chunk) * K) * C + ct * 64;
    int quad = lane >> 4, col = lane & 15;
    #pragma unroll
    for (int i = 0; i < 4; i++) {
        int k = wm * 64 + i * 16 + quad * 4;
        #pragma unroll
        for (int j = 0; j < 2; j++) {
            int c = wn * 32 + j * 16 + col;
            #pragma unroll
            for (int r = 0; r < 4; r++)
                pb[(size_t)(k + r) * C + c] = acc[i][j][r];
        }
    }
}

// ---------------- reduce partials + l2norm over c; emit mu_bf [k][c], muT [c][k] ------------
// On the last EM iteration also writes the fp32 mu tail of `out` directly (kills k_muout).
__global__ void k_norm(const float* __restrict__ part, bf16* __restrict__ mub,
                       bf16* __restrict__ muT, float* __restrict__ outT, int last) {
    int b = blockIdx.x >> 7, k = blockIdx.x & 127, lane = threadIdx.x;  // 64 thr
    float v[4] = {0.f, 0.f, 0.f, 0.f};
    for (int ch = 0; ch < 16; ch++) {
        const float* p = part + ((size_t)(b * 16 + ch) * K + k) * C;
        #pragma unroll
        for (int j = 0; j < 4; j++) v[j] += p[lane + j * 64];
    }
    float s = v[0]*v[0] + v[1]*v[1] + v[2]*v[2] + v[3]*v[3];
    for (int o = 32; o > 0; o >>= 1) s += __shfl_xor(s, o, 64);
    float r = 1.f / (EPSV + sqrtf(s));
    bf16*  mb = mub + ((size_t)b * K + k) * C;
    bf16*  mt = muT + (size_t)b * C * K + k;
    #pragma unroll
    for (int j = 0; j < 4; j++) {
        float val = v[j] * r;
        int c = lane + j * 64;
        mb[c] = __float2bfloat16(val);
        mt[(size_t)c * K] = __float2bfloat16(val);
        if (last) outT[(size_t)b * 32768 + (size_t)c * 128 + k] = val;
    }
}

// ---------------- FUSED q_z + rec: one block = one (img,row y): 64 l' x 128 k ---------------
// Phase 1: acc[j][r] = softmax_k( q[l'][:] . mu[k][:] ).  Phase 2: z routed through padded
// LDS tile (64 x 272B); muT streamed through 2 x 8KB ping-pong halves (128 c-rows each),
// 8 phases (s-chunk x c-half) with counted vmcnt(2) two-barrier pipeline — stage(p+2)
// issued after post-compute barrier so the overwrite target's readers are done.
__global__ void __launch_bounds__(256) k_qzrec(const bf16* __restrict__ P2r,
                                               const bf16* __restrict__ mub,
                                               const bf16* __restrict__ muT,
                                               bf16* __restrict__ P2w) {
    __shared__ __align__(16) char smem[46080];
    char* tA = smem;           // q tile 64x32 = 4KB
    char* tB = smem + 4096;    // mu tile 128x32 = 8KB
    char* zl = smem + 12288;   // z tile 64 x 272B = 17408 (pad kills b128-read conflicts)
    char* mt = smem + 29696;   // muT ping-pong: 2 x 8192 B (128 c-rows x 32 k each)
    int t = threadIdx.x, w = t >> 6, lane = t & 63;
    int b = blockIdx.y, tile = blockIdx.x;          // 0..255
    int n = tile >> 6, y = tile & 63;
    int img = b * NN + n;
    const bf16* Ab = P2r + ((size_t)img * PA + (size_t)(y + 1) * PW + 1) * 512;
    const bf16* Bb = mub + (size_t)b * K * C;
    int srow = t >> 2, sseg = t & 3, aseg = sseg ^ (srow & 3);
    char* dA  = tA + w * 1024;
    char* dB0 = tB + w * 1024;
    char* dB1 = tB + 4096 + w * 1024;
    int q = lane >> 4, col = lane & 15;
    int boff[8], aoff;
    #pragma unroll
    for (int j = 0; j < 8; j++) {
        int rowB = j * 16 + col;
        boff[j] = rowB * 64 + ((q ^ (rowB & 3)) << 4);
    }
    { int rowA = w * 16 + col;
      aoff = rowA * 64 + ((q ^ (rowA & 3)) << 4); }
    f32x4 acc[8];
    #pragma unroll
    for (int j = 0; j < 8; j++) acc[j] = f32x4{0.f, 0.f, 0.f, 0.f};
    for (int s = 0; s < 8; s++) {
        int cb0 = s * 32 + aseg * 8;
        __syncthreads();
        __builtin_amdgcn_global_load_lds(AS1(Ab + (size_t)srow * 512 + cb0),      AS3(dA),  16, 0, 0);
        __builtin_amdgcn_global_load_lds(AS1(Bb + (size_t)srow * C + cb0),        AS3(dB0), 16, 0, 0);
        __builtin_amdgcn_global_load_lds(AS1(Bb + (size_t)(srow + 64) * C + cb0), AS3(dB1), 16, 0, 0);
        __syncthreads();
        bf16x8 af = *(bf16x8*)(tA + aoff);
        #pragma unroll
        for (int j = 0; j < 8; j++) {
            bf16x8 bfr = *(bf16x8*)(tB + boff[j]);
            acc[j] = __builtin_amdgcn_mfma_f32_16x16x32_bf16(af, bfr, acc[j], 0, 0, 0);
        }
    }
    // softmax over k (j, col) per row r; write z into zl[l'][k] (bf16, row stride 272)
    #pragma unroll
    for (int r = 0; r < 4; r++) {
        float mm = acc[0][r];
        #pragma unroll
        for (int j = 1; j < 8; j++) mm = fmaxf(mm, acc[j][r]);
        mm = fmaxf(mm, __shfl_xor(mm, 1, 64));
        mm = fmaxf(mm, __shfl_xor(mm, 2, 64));
        mm = fmaxf(mm, __shfl_xor(mm, 4, 64));
        mm = fmaxf(mm, __shfl_xor(mm, 8, 64));
        float ss = 0.f;
        float e[8];
        #pragma unroll
        for (int j = 0; j < 8; j++) { e[j] = __expf(acc[j][r] - mm); ss += e[j]; }
        ss += __shfl_xor(ss, 1, 64);
        ss += __shfl_xor(ss, 2, 64);
        ss += __shfl_xor(ss, 4, 64);
        ss += __shfl_xor(ss, 8, 64);
        float inv = 1.f / ss;
        int zrow = w * 16 + q * 4 + r;
        #pragma unroll
        for (int j = 0; j < 8; j++)
            *(bf16*)(zl + zrow * 272 + (j * 16 + col) * 2) = __float2bfloat16(e[j] * inv);
    }
    // ---- phase 2 ----
    const bf16* Mb = muT + (size_t)b * C * K;
    // stage phase p (s = p>>1 k-chunk, h = p&1 c-half): rows h*128..+128 -> mt + h*8192
    auto stageMT = [&](int p) {
        int s = p >> 1, h = p & 1;
        #pragma unroll
        for (int it2 = 0; it2 < 2; it2++) {
            int u = it2 * 256 + t;
            int row = u >> 2, seg = u & 3;
            int grow = h * 128 + row;
            int sg = seg ^ ((grow ^ (grow >> 2)) & 3);
            __builtin_amdgcn_global_load_lds(AS1(Mb + (size_t)grow * K + s * 32 + sg * 8),
                AS3(mt + h * 8192 + it2 * 4096 + w * 1024), 16, 0, 0);
        }
    };
    stageMT(0);
    stageMT(1);
    // A-frags from zl: row = w*16+col, k = ch*32 + q*8..+8 (same-wave rows; lgkm-ordered)
    bf16x8 afz[4];
    #pragma unroll
    for (int ch = 0; ch < 4; ch++)
        afz[ch] = *(bf16x8*)(zl + (w * 16 + col) * 272 + ch * 64 + q * 16);
    f32x4 acc2[16];
    #pragma unroll
    for (int j = 0; j < 16; j++) acc2[j] = f32x4{0.f, 0.f, 0.f, 0.f};
    #pragma unroll
    for (int p = 0; p < 8; p++) {
        if (p < 7) asm volatile("s_waitcnt vmcnt(2)" ::: "memory");
        else       asm volatile("s_waitcnt vmcnt(0)" ::: "memory");
        __builtin_amdgcn_s_barrier();
        asm volatile("" ::: "memory");
        const int s = p >> 1, h = p & 1;
        #pragma unroll
        for (int jj = 0; jj < 8; jj++) {
            int j = h * 8 + jj;
            int rr = j * 16 + col;
            int local = rr - h * 128;
            bf16x8 bm = *(bf16x8*)(mt + h * 8192 + local * 64 +
                                   ((q ^ ((rr ^ (rr >> 2)) & 3)) << 4));
            acc2[j] = __builtin_amdgcn_mfma_f32_16x16x32_bf16(afz[s], bm, acc2[j], 0, 0, 0);
        }
        asm volatile("" ::: "memory");
        __builtin_amdgcn_s_barrier();
        asm volatile("" ::: "memory");
        if (p < 6) stageMT(p + 2);
    }
    // store rec to P2 second-half channels; l' = w*16 + q*4 + r, c = j*16 + col
    #pragma unroll
    for (int r = 0; r < 4; r++) {
        int xg = w * 16 + q * 4 + r;
        bf16* dst = P2w + ((size_t)img * PA + (size_t)(y + 1) * PW + xg + 1) * 512 + 256;
        #pragma unroll
        for (int j = 0; j < 16; j++)
            dst[j * 16 + col] = __float2bfloat16(acc2[j][r]);
    }
}

// ---------------- MFMA implicit-GEMM conv: 128oc x 256px (4 out rows) per block -------------
// (R3/R5 version — best measured.) Per step each wave does 32 MFMA from 12 ds_read_b128.
// IN tile [6 rows][66 px][32 ic] = 25344 B staged per chunk; W streams via 3 x 8192 B
// buffers (prefetch distance 2, counted vmcnt(2)). Grid 512 = exactly 2 blocks/CU.
__global__ void __launch_bounds__(256, 2) k_conv(const bf16* __restrict__ P2,
                                                 const bf16* __restrict__ Wb,
                                                 const float* __restrict__ cb,
                                                 float* __restrict__ out) {
    __shared__ __align__(16) char smem[49920];
    char* inl = smem;            // 6*66*32*2 = 25344 B input tile
    char* wld = smem + 25344;    // 3 x 8192 B weight buffers
    int t = threadIdx.x, w = t >> 6, lane = t & 63;
    int m0  = blockIdx.x * 128;
    int y0  = blockIdx.y * 4;    // padded rows y0..y0+5 feed output rows y0..y0+3
    int img = blockIdx.z;
    int srow = t >> 2;
    int aseg = (t & 3) ^ ((srow ^ (srow >> 2)) & 3);     // W stage swizzle (64B rows)
    int wm = w >> 1, wn = w & 1;                          // oc-half / px-half (2 rows)
    int q = lane >> 4, lane15 = lane & 15;

    // A (weights) LDS read offsets within one 8KB buffer (matches stage swizzle)
    int aoff[4];
    #pragma unroll
    for (int i = 0; i < 4; i++) {
        int rowA = wm * 64 + i * 16 + lane15;
        aoff[i] = rowA * 64 + (((q ^ (rowA ^ (rowA >> 2))) & 3) << 4);
    }

    // stage input chunk cc (32 ic): 6 rows x 66 px x 4 seg = 1584 x 16B, linear LDS dest.
    // LDS slot (row, px, s') holds global seg s' ^ ((px ^ (px>>1)) & 3)  (involution).
    auto stageIN = [&](int cc) {
        size_t ibase = (size_t)img * PA * 512 + cc * 32;
        #pragma unroll
        for (int it = 0; it < 6; it++) {
            unsigned g = it * 256 + t;
            unsigned row = g / 264u, ps = g - row * 264u;
            unsigned px = ps >> 2, s0 = ps & 3;
            unsigned sg = s0 ^ ((px ^ (px >> 1)) & 3);
            __builtin_amdgcn_global_load_lds(
                AS1(P2 + ibase + ((size_t)(y0 + row) * PW + px) * 512 + sg * 8),
                AS3(inl + it * 4096 + w * 1024), 16, 0, 0);
        }
        if (t < 48) {   // remainder 1536..1583 (wave 0, lanes 0-47)
            unsigned g = 1536 + t;
            unsigned row = g / 264u, ps = g - row * 264u;
            unsigned px = ps >> 2, s0 = ps & 3;
            unsigned sg = s0 ^ ((px ^ (px >> 1)) & 3);
            __builtin_amdgcn_global_load_lds(
                AS1(P2 + ibase + ((size_t)(y0 + row) * PW + px) * 512 + sg * 8),
                AS3(inl + 24576), 16, 0, 0);
        }
    };

    // acc init with bias: acc[i][j], i = oc-tile (4x16), j = px-tile (2 rows x 4x16)
    f32x4 acc[4][8];
    #pragma unroll
    for (int i = 0; i < 4; i++) {
        int oc = m0 + wm * 64 + i * 16 + q * 4;
        #pragma unroll
        for (int r = 0; r < 4; r++) {
            float bv = cb[oc + r];
            #pragma unroll
            for (int j = 0; j < 8; j++) acc[i][j][r] = bv;
        }
    }

    // prologue: IN(0) + W(tap0,cc0)->buf0, W(tap1,cc0)->buf1; full drain
    stageIN(0);
    {
        const bf16* w0 = Wb + (size_t)(m0 + srow) * IC2 + aseg * 8;
        __builtin_amdgcn_global_load_lds(AS1(w0),                         AS3(wld + w * 1024), 16, 0, 0);
        __builtin_amdgcn_global_load_lds(AS1(w0 + (size_t)64 * IC2),      AS3(wld + 4096 + w * 1024), 16, 0, 0);
        const bf16* w1 = w0 + (size_t)(OC * IC2);
        __builtin_amdgcn_global_load_lds(AS1(w1),                         AS3(wld + 8192 + w * 1024), 16, 0, 0);
        __builtin_amdgcn_global_load_lds(AS1(w1 + (size_t)64 * IC2),      AS3(wld + 8192 + 4096 + w * 1024), 16, 0, 0);
    }
    asm volatile("s_waitcnt vmcnt(0)" ::: "memory");
    __builtin_amdgcn_s_barrier();
    asm volatile("" ::: "memory");

    for (int cc = 0; cc < 16; cc++) {
        #pragma unroll
        for (int rt = 0; rt < 9; rt++) {
            const int dy = rt / 3, dx = rt % 3;
            // ---- W fragments (buffer idx static: rt % 3) ----
            char* wbuf = wld + (rt % 3) * 8192;
            bf16x8 af[4];
            #pragma unroll
            for (int i = 0; i < 4; i++) af[i] = *(bf16x8*)(wbuf + aoff[i]);
            // ---- prefetch W(global step +2) into buffer (rt+2)%3 (prev step's, safe) ----
            const bool doPf = (cc * 9 + rt + 2) < 144;
            if (doPf) {
                const int g2 = rt + 2;
                const int rt2 = (g2 >= 9) ? g2 - 9 : g2;
                const int cc2 = cc + (g2 >= 9 ? 1 : 0);
                char* wdst = wld + ((rt + 2) % 3) * 8192;
                const bf16* wsrc = Wb + (size_t)rt2 * (OC * IC2) + (size_t)(m0 + srow) * IC2
                                 + cc2 * 32 + aseg * 8;
                __builtin_amdgcn_global_load_lds(AS1(wsrc),                    AS3(wdst + w * 1024), 16, 0, 0);
                __builtin_amdgcn_global_load_lds(AS1(wsrc + (size_t)64 * IC2), AS3(wdst + 4096 + w * 1024), 16, 0, 0);
            }
            // ---- MFMA: j = (row 0/1 within px-half) x (4 px-tiles of 16) ----
            __builtin_amdgcn_s_setprio(1);
            #pragma unroll
            for (int j = 0; j < 8; j++) {
                int p = (j & 3) * 16 + lane15 + dx;
                int rowsel = 2 * wn + (j >> 2) + dy;
                bf16x8 bfr = *(bf16x8*)(inl + rowsel * 4224 + p * 64 +
                                        (((q ^ (p ^ (p >> 1))) & 3) << 4));
                #pragma unroll
                for (int i = 0; i < 4; i++)
                    acc[i][j] = __builtin_amdgcn_mfma_f32_16x16x32_bf16(af[i], bfr, acc[i][j], 0, 0, 0);
            }
            __builtin_amdgcn_s_setprio(0);
            // ---- waits + barriers ----
            if (rt == 8) {
                if (cc < 15) {   // chunk boundary: re-stage IN, full drain
                    asm volatile("" ::: "memory");
                    __builtin_amdgcn_s_barrier();
                    asm volatile("" ::: "memory");
                    stageIN(cc + 1);
                    asm volatile("s_waitcnt vmcnt(0)" ::: "memory");
                    __builtin_amdgcn_s_barrier();
                    asm volatile("" ::: "memory");
                }
                // cc==15: last step, fall through to epilogue
            } else {
                if (doPf) asm volatile("s_waitcnt vmcnt(2)" ::: "memory");
                else      asm volatile("s_waitcnt vmcnt(0)" ::: "memory");
                __builtin_amdgcn_s_barrier();
                asm volatile("" ::: "memory");
            }
        }
    }

    // epilogue: store (bias already in acc)
    #pragma unroll
    for (int i = 0; i < 4; i++) {
        int oc = m0 + wm * 64 + i * 16 + q * 4;
        #pragma unroll
        for (int j = 0; j < 8; j++) {
            int px = blockIdx.y * 256 + wn * 128 + (j >> 2) * 64 + (j & 3) * 16 + lane15;
            #pragma unroll
            for (int r = 0; r < 4; r++)
                out[((size_t)img * OC + oc + r) * L + px] = acc[i][j][r];
        }
    }
}

extern "C" void kernel_launch(void* const* d_in, const int* in_sizes, int n_in,
                              void* d_out, int out_size, void* d_ws, size_t ws_size,
                              hipStream_t stream) {
    const float* x   = (const float*)d_in[0];   // [4][256][4096]
    const float* qy  = (const float*)d_in[1];   // [16][256][4096]
    const float* mu0 = (const float*)d_in[2];   // [256][128]
    const float* cw  = (const float*)d_in[3];   // [256][512][3][3]
    const float* cb  = (const float*)d_in[4];   // [256]
    float* out = (float*)d_out;

    // workspace layout (bytes):
    //   mu_bf  @ 524288    (256 KB bf16 [b][k][c])
    //   muT_bf @ 786432    (256 KB bf16 [b][c][k])
    //   Wb     @ 1048576   (2.25 MB bf16 [9][oc][ic])
    //   zt     @ 3407872   (EM zt bf16 [b][k][l] 4.19MB; dead after EM)
    //   P2     @ 20185088  (71.37 MB bf16 [16][66*66][512])
    //     EM-lifetime overlays inside P2: x_bf @+0 (8.39MB), part @+8388608 (8.39MB fp32),
    //     xt @+16777216 (8.39MB) — all dead before P2 is first written (after EM).
    char* ws = (char*)d_ws;
    bf16*  mu_b = (bf16*) (ws + 524288);
    bf16*  muT  = (bf16*) (ws + 786432);
    bf16*  Wb   = (bf16*) (ws + 1048576);
    bf16*  zt   = (bf16*) (ws + 3407872);
    bf16*  P2   = (bf16*) (ws + 20185088);
    bf16*  x_bf = (bf16*) (ws + 20185088);
    float* part = (float*)(ws + 20185088 + 8388608);
    bf16*  xt   = (bf16*) (ws + 20185088 + 16777216);

    k_init<<<512, 256, 0, stream>>>(mu0, mu_b);
    k_prepx<<<dim3(64, 4, 4), 256, 0, stream>>>(x, x_bf, xt);

    for (int it = 0; it < 5; it++) {
        k_z<<<dim3(64, 4), 256, 0, stream>>>(xt, mu_b, zt);
        k_mu<<<dim3(4, 16, 4), 256, 0, stream>>>(zt, x_bf, part);
        k_norm<<<512, 64, 0, stream>>>(part, mu_b, muT, out + 16777216, it == 4 ? 1 : 0);
    }

    k_mid<<<9744, 256, 0, stream>>>(qy, P2, cw, Wb);

    k_qzrec<<<dim3(256, 4), 256, 0, stream>>>(P2, mu_b, muT, P2);
    k_conv<<<dim3(2, 16, 16), 256, 0, stream>>>(P2, Wb, cb, out);
}